// Round 1
// 450.445 us; speedup vs baseline: 1.1352x; 1.1352x over previous
//
#include <hip/hip_runtime.h>

#define EPS 0.001f

typedef __attribute__((ext_vector_type(8))) short bf16x8;
typedef __attribute__((ext_vector_type(4))) short bf16x4;
typedef __attribute__((ext_vector_type(4))) float f32x4;

// ---- problem sizes ----
constexpr int Bn = 8, Tx = 20, Dx = 24, Hx = 24, Wx = 24;
constexpr int Cmid = 12, CoutN = 36;
constexpr int T1 = 18, D1 = 22;
constexpr int T2 = 16, D2 = 20;

// x strides (fp32)
constexpr int SXD = 576, SXT = 13824, SXC = 276480;
constexpr long SXB = 1105920;

// xt: [b][t20][d24][h24][w24][c4] bf16
constexpr int XTD = 2304, XTT = 55296;
constexpr long XTB = (long)Tx * XTT;     // 1105920

// h1t: [b][t18][d22][h22][w22][c16] bf16
constexpr int HTW = 16;
constexpr int HTH = 22 * 16;          // 352
constexpr int HTD = 22 * 22 * 16;     // 7744
constexpr int HTT = 22 * HTD;         // 170368
constexpr long HTB = (long)T1 * HTT;  // 3066624

// out strides (fp32)
constexpr int S2D = 400, S2T = 8000, S2O = 128000;
constexpr long S2B = 4608000;

constexpr int NBLK1 = 8 * 18 * 22;    // 3168 conv1m blocks

__device__ __forceinline__ unsigned short f2bf(float f) {
    unsigned u = __builtin_bit_cast(unsigned, f);
    u = (u + 0x7fffu + ((u >> 16) & 1u)) >> 16;
    return (unsigned short)u;
}

// async global->LDS, 16B per lane. LDS dest is wave-uniform base; HW adds lane*16.
__device__ __forceinline__ void gload16(const void* g, void* l) {
    __builtin_amdgcn_global_load_lds(
        (const __attribute__((address_space(1))) void*)g,
        (__attribute__((address_space(3))) void*)l, 16, 0, 0);
}

// x [b][cin][t][d][h][w] fp32 -> xt [b][t][d][h][w][c4] bf16
__global__ __launch_bounds__(576) void k_xt(const float* __restrict__ x,
                                            unsigned short* __restrict__ xt) {
    const int tid = threadIdx.x;          // 0..575 = h*24+w
    const int d = blockIdx.x, t = blockIdx.y, b = blockIdx.z;
    const float* src = x + (long)b * SXB + (long)t * SXT + (long)d * SXD + tid;
    float v0 = src[0];
    float v1 = src[SXC];
    float v2 = src[2 * SXC];
    float v3 = src[3 * SXC];
    uint2 p;
    p.x = (unsigned)f2bf(v0) | ((unsigned)f2bf(v1) << 16);
    p.y = (unsigned)f2bf(v2) | ((unsigned)f2bf(v3) << 16);
    *(uint2*)(xt + (long)b * XTB + (long)t * XTT + (long)d * XTD + tid * 4) = p;
}

// Build conv1 A-fragments Wf1[p=0..13][lane][8]
__global__ void k_finW1(const float* __restrict__ W1, unsigned short* __restrict__ Wf1) {
    const int p = blockIdx.x;        // 0..13
    const int lane = threadIdx.x;    // 0..63
    const int m = lane & 15;
    const int q = lane >> 4;
    unsigned short vals[8];
#pragma unroll
    for (int j = 0; j < 8; ++j) {
        int kk = q * 8 + j;
        int g = 2 * p + (kk >> 4);
        int r = kk & 15;
        int kw = r >> 2, cin = r & 3;
        float v = 0.f;
        if (m < 12 && kw < 3 && g < 27) {
            int kt = g / 9, g9 = g - kt * 9, kd = g9 / 3, kh = g9 - kd * 3;
            v = W1[m * 324 + cin * 81 + kt * 27 + kd * 9 + kh * 3 + kw];
        }
        vals[j] = f2bf(v);
    }
    uint4 pk;
    pk.x = (unsigned)vals[0] | ((unsigned)vals[1] << 16);
    pk.y = (unsigned)vals[2] | ((unsigned)vals[3] << 16);
    pk.z = (unsigned)vals[4] | ((unsigned)vals[5] << 16);
    pk.w = (unsigned)vals[6] | ((unsigned)vals[7] << 16);
    *(uint4*)(Wf1 + p * 512 + lane * 8) = pk;
}

// MFMA implicit-GEMM conv1. 1D grid 3168, XCD-swizzled.
__global__ __launch_bounds__(512, 4) void k_conv1m(
    const unsigned short* __restrict__ xt, const unsigned short* __restrict__ Wf1,
    const float* __restrict__ b1, unsigned short* __restrict__ h1t,
    float* __restrict__ part)
{
    __shared__ char lds[9 * 4608 + 16];
    __shared__ float ssum[8][12], ssq[8][12];

    const int tid  = threadIdx.x;
    const int lane = tid & 63;
    const int wv   = tid >> 6;     // 0..7

    // XCD-aware swizzle: 3168 % 8 == 0, each XCD gets one full b (396 blocks)
    const int l  = blockIdx.x;
    const int sw = (l & 7) * 396 + (l >> 3);
    const int d  = sw % 22;
    const int tt = sw / 22;
    const int t  = tt % 18;
    const int b  = tt / 18;
    const int bid = (b * 18 + t) * 22 + d;

    const int n16 = lane & 15;
    const int q   = lane >> 4;

    // stage 9 planes: p = kt*3+kd
    {
        for (int i = tid; i < 2592; i += 512) {
            int p = i / 288, r = i - p * 288;
            int kt = p / 3, kd = p - kt * 3;
            const unsigned short* src = xt + (long)b * XTB + (long)(t + kt) * XTT
                                      + (long)(d + kd) * XTD + r * 8;
            *(uint4*)(lds + i * 16) = *(const uint4*)src;
        }
    }

    // A fragments (global, L2-resident)
    bf16x8 A[14];
#pragma unroll
    for (int p = 0; p < 14; ++p)
        A[p] = *(const bf16x8*)(Wf1 + p * 512 + lane * 8);

    // per-tile position info
    int hh[4], ww[4], nn[4];
#pragma unroll
    for (int u = 0; u < 4; ++u) {
        int n = (wv * 4 + u) * 16 + n16;
        nn[u] = n;
        int nc = n < 484 ? n : 483;
        hh[u] = nc / 22;
        ww[u] = nc - hh[u] * 22;
    }

    f32x4 acc[4];
#pragma unroll
    for (int u = 0; u < 4; ++u) acc[u] = (f32x4){0.f, 0.f, 0.f, 0.f};

    __syncthreads();

#pragma unroll
    for (int p = 0; p < 14; ++p) {
        int gq = 2 * p + (q >> 1);
        int gc = gq < 27 ? gq : 26;
        int kt = gc / 9, g9 = gc - kt * 9, kd = g9 / 3, kh = g9 - kd * 3;
        const int off = (kt * 3 + kd) * 4608 + kh * 192 + (q & 1) * 16;
#pragma unroll
        for (int u = 0; u < 4; ++u) {
            const int addr = off + hh[u] * 192 + ww[u] * 8;
            bf16x4 lo = *(const bf16x4*)(lds + addr);
            bf16x4 hi = *(const bf16x4*)(lds + addr + 8);
            bf16x8 bb;
            bb[0] = lo[0]; bb[1] = lo[1]; bb[2] = lo[2]; bb[3] = lo[3];
            bb[4] = hi[0]; bb[5] = hi[1]; bb[6] = hi[2]; bb[7] = hi[3];
            acc[u] = __builtin_amdgcn_mfma_f32_16x16x32_bf16(A[p], bb, acc[u], 0, 0, 0);
        }
    }

    // epilogue: D row = q*4+r = cout, col = n16 = position
    const int c0 = q * 4;
    float bias[4];
#pragma unroll
    for (int r = 0; r < 4; ++r) bias[r] = (c0 + r) < 12 ? b1[c0 + r] : 0.f;

    float ls[4] = {0.f, 0.f, 0.f, 0.f}, lq[4] = {0.f, 0.f, 0.f, 0.f};
#pragma unroll
    for (int u = 0; u < 4; ++u) {
        const bool valid = nn[u] < 484;
        float v[4];
#pragma unroll
        for (int r = 0; r < 4; ++r) {
            float val = fmaxf(acc[u][r] + bias[r], 0.f);
            v[r] = val;
            if (valid) { ls[r] += val; lq[r] += val * val; }
        }
        if (valid) {
            const long ob = (long)b * HTB + (long)t * HTT + (long)d * HTD
                          + (long)hh[u] * HTH + (long)ww[u] * HTW + c0;
            uint2 pk;
            pk.x = (unsigned)f2bf(v[0]) | ((unsigned)f2bf(v[1]) << 16);
            pk.y = (unsigned)f2bf(v[2]) | ((unsigned)f2bf(v[3]) << 16);
            *(uint2*)(h1t + ob) = pk;
        }
    }

    // stats: reduce over n16 within q-group
#pragma unroll
    for (int off = 8; off > 0; off >>= 1) {
#pragma unroll
        for (int r = 0; r < 4; ++r) {
            ls[r] += __shfl_xor(ls[r], off);
            lq[r] += __shfl_xor(lq[r], off);
        }
    }
    if (n16 == 0 && q < 3) {
#pragma unroll
        for (int r = 0; r < 4; ++r) {
            ssum[wv][c0 + r] = ls[r];
            ssq[wv][c0 + r] = lq[r];
        }
    }
    __syncthreads();
    // part transposed: part[ch][bid] so k_red reads coalesced
    if (tid < 12) {
        float s = 0.f;
#pragma unroll
        for (int i = 0; i < 8; ++i) s += ssum[i][tid];
        part[tid * NBLK1 + bid] = s;
    } else if (tid < 24) {
        float s = 0.f;
#pragma unroll
        for (int i = 0; i < 8; ++i) s += ssq[i][tid - 12];
        part[tid * NBLK1 + bid] = s;
    }
}

// deterministic cross-block reduction: 24 blocks, one per stat channel
__global__ void k_red(const float* __restrict__ part, float* __restrict__ stats2) {
    __shared__ float s[256];
    const int c = blockIdx.x;
    const int tid = threadIdx.x;
    float acc = 0.f;
    for (int i = tid; i < NBLK1; i += 256) acc += part[c * NBLK1 + i];
    s[tid] = acc;
    __syncthreads();
    for (int off = 128; off > 0; off >>= 1) {
        if (tid < off) s[tid] += s[tid + off];
        __syncthreads();
    }
    if (tid == 0) stats2[c] = s[0];
}

// finalize BN, parallel tap-sum: 432 threads each do one (o,c) 81-tap sum
__global__ void k_fin1(const float* __restrict__ stats2, const float* __restrict__ gamma,
                       const float* __restrict__ beta, const float* __restrict__ W2,
                       const float* __restrict__ b2, float* __restrict__ abuf,
                       float* __restrict__ b2ws)
{
    __shared__ float d_s[12];
    __shared__ float red[36][12];
    const int tid = threadIdx.x;  // 512
    if (tid < 12) {
        const float N = 1533312.f;   // 8*18*22*22*22
        float mean = stats2[tid] / N;
        float var  = stats2[12 + tid] / N - mean * mean;
        float a = gamma[tid] * rsqrtf(var + EPS);
        abuf[tid] = a;
        d_s[tid] = beta[tid] - mean * a;
    }
    __syncthreads();
    if (tid < 432) {
        const int o = tid / 12, c = tid - o * 12;
        const float* p = W2 + o * 972 + c * 81;
        float ts = 0.f;
#pragma unroll
        for (int k = 0; k < 81; ++k) ts += p[k];
        red[o][c] = d_s[c] * ts;
    }
    __syncthreads();
    if (tid < 36) {
        float s = b2[tid];
#pragma unroll
        for (int c = 0; c < 12; ++c) s += red[tid][c];
        b2ws[tid] = s;
    }
}

// Build conv2 A-operand fragment-ordered weights Wf (BN-scaled).
__global__ void k_fin2(const float* __restrict__ W2, const float* __restrict__ abuf,
                       unsigned short* __restrict__ Wf)
{
    const int bi = blockIdx.x;       // 0..161
    const int lane = threadIdx.x;    // 0..63
    const int ch = bi & 1;
    const int tmp = bi >> 1;
    const int mt = tmp % 3;
    const int g = tmp / 3;
    const int kt = g / 9, g9 = g % 9, kd = g9 / 3, kh = g9 % 3;
    const int o = mt * 16 + (lane & 15);

    unsigned short vals[8];
#pragma unroll
    for (int j = 0; j < 8; ++j) {
        int k = ch * 32 + ((lane >> 4) << 3) + j;
        float v = 0.f;
        if (k < 48 && o < 36) {
            int kw = k >> 4, c = k & 15;
            if (c < 12)
                v = W2[o * 972 + c * 81 + kt * 27 + kd * 9 + kh * 3 + kw] * abuf[c];
        }
        vals[j] = f2bf(v);
    }
    uint4 pk;
    pk.x = (unsigned)vals[0] | ((unsigned)vals[1] << 16);
    pk.y = (unsigned)vals[2] | ((unsigned)vals[3] << 16);
    pk.z = (unsigned)vals[4] | ((unsigned)vals[5] << 16);
    pk.w = (unsigned)vals[6] | ((unsigned)vals[7] << 16);
    *(uint4*)(Wf + bi * 512 + lane * 8) = pk;
}

// MFMA implicit-GEMM conv2, v2:
//  - LDS holds h1t slab in NATURAL layout (3 d-planes, [pl][h22][w22][c16]),
//    staged via global_load_lds width=16 (no permutation, no VGPR round trip).
//    B-fragment read: addr = pl*15488 + (h+kh)*704 + w*32 + q*16 (chunk1: +64,
//    (q&1)*16) -- consecutive 16B units across the wave => near-uniform banks.
//  - A-fragment 1-deep software pipeline across g (hides L2 latency).
//  - XCD-swizzled 1D grid (2560 % 8 == 0): each XCD works one b => h1t slabs
//    stay L2-resident across d/t neighbors.
__global__ __launch_bounds__(320, 3) void k_conv2m(
    const unsigned short* __restrict__ h1t, const unsigned short* __restrict__ Wf,
    const float* __restrict__ b2ws, float* __restrict__ out)
{
    __shared__ char lds[2944 * 16];   // 47104 B (2904 units needed, staged 2944)

    const int tid  = threadIdx.x;
    const int lane = tid & 63;
    const int wv   = tid >> 6;     // 0..4

    const int l  = blockIdx.x;
    const int sw = (l & 7) * 320 + (l >> 3);   // bijective, 2560 % 8 == 0
    const int d  = sw % 20;
    const int tq = sw / 20;
    const int t  = tq & 15;
    const int b  = tq >> 4;

    const int n16 = lane & 15;
    const int q   = lane >> 4;

    int posb[5], pb[5];
#pragma unroll
    for (int u = 0; u < 5; ++u) {
        int p = (wv * 5 + u) * 16 + n16;       // 0..399, exact tiling
        int h = p / 20, w = p - h * 20;
        pb[u] = p;
        posb[u] = h * 704 + w * 32;
    }
    const int qb0 = q * 16;                     // tap w+(q>>1), half q&1
    const int qb1 = (q & 1) * 16 + 64;          // tap w+2 (q>=2 -> x0 weights)

    f32x4 acc[5][3];
#pragma unroll
    for (int u = 0; u < 5; ++u)
#pragma unroll
        for (int mt = 0; mt < 3; ++mt)
            acc[u][mt] = (f32x4){0.f, 0.f, 0.f, 0.f};

    // A pipeline: preload g=0
    bf16x8 A0[3][2];
#pragma unroll
    for (int mt = 0; mt < 3; ++mt)
#pragma unroll
        for (int c2 = 0; c2 < 2; ++c2)
            A0[mt][c2] = *(const bf16x8*)(Wf + ((mt * 2 + c2) << 9) + lane * 8);

    for (int kt = 0; kt < 3; ++kt) {
        __syncthreads();   // prior reads done before overwrite
        {
            const unsigned short* src = h1t + (long)b * HTB + (long)(t + kt) * HTT
                                      + (long)d * HTD;
            // 2944 units of 16B: 9 rounds x 320 lanes + one wave0 round.
            // (40-unit global over-read stays inside the h1t workspace region.)
#pragma unroll
            for (int r = 0; r < 9; ++r) {
                const int u0 = r * 320 + wv * 64;
                gload16(src + (long)(u0 + lane) * 8, lds + u0 * 16);
            }
            if (wv == 0)
                gload16(src + (long)(2880 + lane) * 8, lds + 2880 * 16);
        }
        __syncthreads();   // drains vmcnt -> slab visible

        for (int g9 = 0; g9 < 9; ++g9) {
            const int g  = kt * 9 + g9;
            const int gn = (g < 26) ? g + 1 : 26;
            const int kd = g9 / 3, kh = g9 - kd * 3;
            const int goff = kd * 15488 + kh * 704;

            // prefetch next g's A fragments (used next iteration)
            bf16x8 A1[3][2];
#pragma unroll
            for (int mt = 0; mt < 3; ++mt)
#pragma unroll
                for (int c2 = 0; c2 < 2; ++c2)
                    A1[mt][c2] = *(const bf16x8*)(Wf + (((gn * 3 + mt) * 2 + c2) << 9) + lane * 8);

#pragma unroll
            for (int u = 0; u < 5; ++u) {
                const char* bbase = lds + posb[u] + goff;
                bf16x8 b0 = *(const bf16x8*)(bbase + qb0);
                bf16x8 b1 = *(const bf16x8*)(bbase + qb1);
#pragma unroll
                for (int mt = 0; mt < 3; ++mt) {
                    acc[u][mt] = __builtin_amdgcn_mfma_f32_16x16x32_bf16(A0[mt][0], b0, acc[u][mt], 0, 0, 0);
                    acc[u][mt] = __builtin_amdgcn_mfma_f32_16x16x32_bf16(A0[mt][1], b1, acc[u][mt], 0, 0, 0);
                }
            }
#pragma unroll
            for (int mt = 0; mt < 3; ++mt)
#pragma unroll
                for (int c2 = 0; c2 < 2; ++c2)
                    A0[mt][c2] = A1[mt][c2];
        }
    }

    const long ob = (long)b * S2B + (long)t * S2T + (long)d * S2D;
#pragma unroll
    for (int mt = 0; mt < 3; ++mt)
#pragma unroll
    for (int r = 0; r < 4; ++r) {
        const int o = mt * 16 + q * 4 + r;
        if (o < 36) {
            const float bias = b2ws[o];
#pragma unroll
            for (int u = 0; u < 5; ++u)
                out[ob + (long)o * S2O + pb[u]] = fmaxf(acc[u][mt][r] + bias, 0.f);
        }
    }
}

extern "C" void kernel_launch(void* const* d_in, const int* in_sizes, int n_in,
                              void* d_out, int out_size, void* d_ws, size_t ws_size,
                              hipStream_t stream) {
    const float* x     = (const float*)d_in[0];
    const float* W1    = (const float*)d_in[1];
    const float* b1    = (const float*)d_in[2];
    const float* gamma = (const float*)d_in[3];
    const float* beta  = (const float*)d_in[4];
    const float* W2    = (const float*)d_in[5];
    const float* b2    = (const float*)d_in[6];
    float* out = (float*)d_out;

    float* ws     = (float*)d_ws;
    float* stats2 = ws;                                  // 24 f
    float* abuf   = ws + 32;                             // 12 f
    float* b2ws   = ws + 64;                             // 36 f
    unsigned short* Wf1 = (unsigned short*)((char*)d_ws + 1024);    // 14336 B
    unsigned short* Wf  = (unsigned short*)((char*)d_ws + 16384);   // 165888 B
    float* part   = (float*)((char*)d_ws + 196608);      // 24*3168 f = 304128 B
    unsigned short* h1t = (unsigned short*)((char*)d_ws + 524288);  // 49.07 MB
    unsigned short* xt  = (unsigned short*)((char*)d_ws + 50331648); // 17.7 MB

    k_xt<<<dim3(24, 20, 8), 576, 0, stream>>>(x, xt);
    k_finW1<<<14, 64, 0, stream>>>(W1, Wf1);
    k_conv1m<<<3168, 512, 0, stream>>>(xt, Wf1, b1, h1t, part);
    k_red<<<24, 256, 0, stream>>>(part, stats2);
    k_fin1<<<1, 512, 0, stream>>>(stats2, gamma, beta, W2, b2, abuf, b2ws);
    k_fin2<<<162, 64, 0, stream>>>(W2, abuf, Wf);
    k_conv2m<<<2560, 320, 0, stream>>>(h1t, Wf, b2ws, out);
}

// Round 2
// 420.465 us; speedup vs baseline: 1.2161x; 1.0713x over previous
//
#include <hip/hip_runtime.h>

#define EPS 0.001f

typedef __attribute__((ext_vector_type(8))) short bf16x8;
typedef __attribute__((ext_vector_type(4))) short bf16x4;
typedef __attribute__((ext_vector_type(4))) float f32x4;

// ---- problem sizes ----
constexpr int Bn = 8, Tx = 20, Dx = 24, Hx = 24, Wx = 24;
constexpr int Cmid = 12, CoutN = 36;
constexpr int T1 = 18, D1 = 22;
constexpr int T2 = 16, D2 = 20;

// x strides (fp32)
constexpr int SXD = 576, SXT = 13824, SXC = 276480;
constexpr long SXB = 1105920;

// xt: [b][t20][d24][h24][w24][c4] bf16
constexpr int XTD = 2304, XTT = 55296;
constexpr long XTB = (long)Tx * XTT;     // 1105920

// h1t: [b][t18][d22][h22][w22][c16] bf16
constexpr int HTW = 16;
constexpr int HTH = 22 * 16;          // 352
constexpr int HTD = 22 * 22 * 16;     // 7744
constexpr int HTT = 22 * HTD;         // 170368
constexpr long HTB = (long)T1 * HTT;  // 3066624

// out strides (fp32)
constexpr int S2D = 400, S2T = 8000, S2O = 128000;
constexpr long S2B = 4608000;

constexpr int NBLK1 = 8 * 18 * 22;    // 3168 conv1m blocks

// conv2 LDS layout
constexpr int SLAB_B_SZ = 49152;            // 3072 units * 16B (2904 real + pad)
constexpr int ABUF_OFF  = 2 * SLAB_B_SZ;    // 98304
constexpr int ABUF_SZ   = 12288;            // 12 frags * 1024B
constexpr int LDS_TOT   = ABUF_OFF + 2 * ABUF_SZ;  // 122880

__device__ __forceinline__ unsigned short f2bf(float f) {
    unsigned u = __builtin_bit_cast(unsigned, f);
    u = (u + 0x7fffu + ((u >> 16) & 1u)) >> 16;
    return (unsigned short)u;
}

// async global->LDS, 16B per lane. LDS dest is wave-uniform base; HW adds lane*16.
__device__ __forceinline__ void gload16(const void* g, void* l) {
    __builtin_amdgcn_global_load_lds(
        (const __attribute__((address_space(1))) void*)g,
        (__attribute__((address_space(3))) void*)l, 16, 0, 0);
}

template<int N> __device__ __forceinline__ void waitvm() {
    asm volatile("s_waitcnt vmcnt(%0)" :: "i"(N) : "memory");
}

// x [b][cin][t][d][h][w] fp32 -> xt [b][t][d][h][w][c4] bf16
__global__ __launch_bounds__(576) void k_xt(const float* __restrict__ x,
                                            unsigned short* __restrict__ xt) {
    const int tid = threadIdx.x;          // 0..575 = h*24+w
    const int d = blockIdx.x, t = blockIdx.y, b = blockIdx.z;
    const float* src = x + (long)b * SXB + (long)t * SXT + (long)d * SXD + tid;
    float v0 = src[0];
    float v1 = src[SXC];
    float v2 = src[2 * SXC];
    float v3 = src[3 * SXC];
    uint2 p;
    p.x = (unsigned)f2bf(v0) | ((unsigned)f2bf(v1) << 16);
    p.y = (unsigned)f2bf(v2) | ((unsigned)f2bf(v3) << 16);
    *(uint2*)(xt + (long)b * XTB + (long)t * XTT + (long)d * XTD + tid * 4) = p;
}

// Build conv1 A-fragments Wf1[p=0..13][lane][8]
__global__ void k_finW1(const float* __restrict__ W1, unsigned short* __restrict__ Wf1) {
    const int p = blockIdx.x;        // 0..13
    const int lane = threadIdx.x;    // 0..63
    const int m = lane & 15;
    const int q = lane >> 4;
    unsigned short vals[8];
#pragma unroll
    for (int j = 0; j < 8; ++j) {
        int kk = q * 8 + j;
        int g = 2 * p + (kk >> 4);
        int r = kk & 15;
        int kw = r >> 2, cin = r & 3;
        float v = 0.f;
        if (m < 12 && kw < 3 && g < 27) {
            int kt = g / 9, g9 = g - kt * 9, kd = g9 / 3, kh = g9 - kd * 3;
            v = W1[m * 324 + cin * 81 + kt * 27 + kd * 9 + kh * 3 + kw];
        }
        vals[j] = f2bf(v);
    }
    uint4 pk;
    pk.x = (unsigned)vals[0] | ((unsigned)vals[1] << 16);
    pk.y = (unsigned)vals[2] | ((unsigned)vals[3] << 16);
    pk.z = (unsigned)vals[4] | ((unsigned)vals[5] << 16);
    pk.w = (unsigned)vals[6] | ((unsigned)vals[7] << 16);
    *(uint4*)(Wf1 + p * 512 + lane * 8) = pk;
}

// MFMA implicit-GEMM conv1. 1D grid 3168, XCD-swizzled. gload_lds staging.
__global__ __launch_bounds__(512, 4) void k_conv1m(
    const unsigned short* __restrict__ xt, const unsigned short* __restrict__ Wf1,
    const float* __restrict__ b1, unsigned short* __restrict__ h1t,
    float* __restrict__ part)
{
    __shared__ char lds[9 * 4608 + 16];
    __shared__ float ssum[8][12], ssq[8][12];

    const int tid  = threadIdx.x;
    const int lane = tid & 63;
    const int wv   = tid >> 6;     // 0..7

    // XCD-aware swizzle: 3168 % 8 == 0, each XCD gets one full b (396 blocks)
    const int l  = blockIdx.x;
    const int sw = (l & 7) * 396 + (l >> 3);
    const int d  = sw % 22;
    const int tt = sw / 22;
    const int t  = tt % 18;
    const int b  = tt / 18;
    const int bid = (b * 18 + t) * 22 + d;

    const int n16 = lane & 15;
    const int q   = lane >> 4;

    // stage 9 planes (p = kt*3+kd) via global_load_lds, 2592 units of 16B
    {
#pragma unroll
        for (int r = 0; r < 5; ++r) {
            int i = r * 512 + tid;
            int p = i / 288, rr = i - p * 288;
            int kt = p / 3, kd = p - kt * 3;
            const unsigned short* src = xt + (long)b * XTB + (long)(t + kt) * XTT
                                      + (long)(d + kd) * XTD + rr * 8;
            gload16(src, lds + (r * 512 + wv * 64) * 16);
        }
        if (tid < 32) {   // tail 32 units, wave0 lanes 0..31 (exec-masked)
            int i = 2560 + tid;
            int p = i / 288, rr = i - p * 288;   // all p == 8
            int kt = p / 3, kd = p - kt * 3;
            const unsigned short* src = xt + (long)b * XTB + (long)(t + kt) * XTT
                                      + (long)(d + kd) * XTD + rr * 8;
            gload16(src, lds + 2560 * 16);
        }
    }

    // A fragments (global, L2-resident)
    bf16x8 A[14];
#pragma unroll
    for (int p = 0; p < 14; ++p)
        A[p] = *(const bf16x8*)(Wf1 + p * 512 + lane * 8);

    // per-tile position info
    int hh[4], ww[4], nn[4];
#pragma unroll
    for (int u = 0; u < 4; ++u) {
        int n = (wv * 4 + u) * 16 + n16;
        nn[u] = n;
        int nc = n < 484 ? n : 483;
        hh[u] = nc / 22;
        ww[u] = nc - hh[u] * 22;
    }

    f32x4 acc[4];
#pragma unroll
    for (int u = 0; u < 4; ++u) acc[u] = (f32x4){0.f, 0.f, 0.f, 0.f};

    __syncthreads();   // drains vmcnt -> staged planes visible

#pragma unroll
    for (int p = 0; p < 14; ++p) {
        int gq = 2 * p + (q >> 1);
        int gc = gq < 27 ? gq : 26;
        int kt = gc / 9, g9 = gc - kt * 9, kd = g9 / 3, kh = g9 - kd * 3;
        const int off = (kt * 3 + kd) * 4608 + kh * 192 + (q & 1) * 16;
#pragma unroll
        for (int u = 0; u < 4; ++u) {
            const int addr = off + hh[u] * 192 + ww[u] * 8;
            bf16x4 lo = *(const bf16x4*)(lds + addr);
            bf16x4 hi = *(const bf16x4*)(lds + addr + 8);
            bf16x8 bb;
            bb[0] = lo[0]; bb[1] = lo[1]; bb[2] = lo[2]; bb[3] = lo[3];
            bb[4] = hi[0]; bb[5] = hi[1]; bb[6] = hi[2]; bb[7] = hi[3];
            acc[u] = __builtin_amdgcn_mfma_f32_16x16x32_bf16(A[p], bb, acc[u], 0, 0, 0);
        }
    }

    // epilogue: D row = q*4+r = cout, col = n16 = position
    const int c0 = q * 4;
    float bias[4];
#pragma unroll
    for (int r = 0; r < 4; ++r) bias[r] = (c0 + r) < 12 ? b1[c0 + r] : 0.f;

    float ls[4] = {0.f, 0.f, 0.f, 0.f}, lq[4] = {0.f, 0.f, 0.f, 0.f};
#pragma unroll
    for (int u = 0; u < 4; ++u) {
        const bool valid = nn[u] < 484;
        float v[4];
#pragma unroll
        for (int r = 0; r < 4; ++r) {
            float val = fmaxf(acc[u][r] + bias[r], 0.f);
            v[r] = val;
            if (valid) { ls[r] += val; lq[r] += val * val; }
        }
        if (valid) {
            const long ob = (long)b * HTB + (long)t * HTT + (long)d * HTD
                          + (long)hh[u] * HTH + (long)ww[u] * HTW + c0;
            uint2 pk;
            pk.x = (unsigned)f2bf(v[0]) | ((unsigned)f2bf(v[1]) << 16);
            pk.y = (unsigned)f2bf(v[2]) | ((unsigned)f2bf(v[3]) << 16);
            *(uint2*)(h1t + ob) = pk;
        }
    }

    // stats: reduce over n16 within q-group
#pragma unroll
    for (int off = 8; off > 0; off >>= 1) {
#pragma unroll
        for (int r = 0; r < 4; ++r) {
            ls[r] += __shfl_xor(ls[r], off);
            lq[r] += __shfl_xor(lq[r], off);
        }
    }
    if (n16 == 0 && q < 3) {
#pragma unroll
        for (int r = 0; r < 4; ++r) {
            ssum[wv][c0 + r] = ls[r];
            ssq[wv][c0 + r] = lq[r];
        }
    }
    __syncthreads();
    // part transposed: part[ch][bid] so k_red reads coalesced
    if (tid < 12) {
        float s = 0.f;
#pragma unroll
        for (int i = 0; i < 8; ++i) s += ssum[i][tid];
        part[tid * NBLK1 + bid] = s;
    } else if (tid < 24) {
        float s = 0.f;
#pragma unroll
        for (int i = 0; i < 8; ++i) s += ssq[i][tid - 12];
        part[tid * NBLK1 + bid] = s;
    }
}

// deterministic cross-block reduction: 24 blocks, one per stat channel
__global__ void k_red(const float* __restrict__ part, float* __restrict__ stats2) {
    __shared__ float s[256];
    const int c = blockIdx.x;
    const int tid = threadIdx.x;
    float acc = 0.f;
    for (int i = tid; i < NBLK1; i += 256) acc += part[c * NBLK1 + i];
    s[tid] = acc;
    __syncthreads();
    for (int off = 128; off > 0; off >>= 1) {
        if (tid < off) s[tid] += s[tid + off];
        __syncthreads();
    }
    if (tid == 0) stats2[c] = s[0];
}

// finalize BN, parallel tap-sum: 432 threads each do one (o,c) 81-tap sum
__global__ void k_fin1(const float* __restrict__ stats2, const float* __restrict__ gamma,
                       const float* __restrict__ beta, const float* __restrict__ W2,
                       const float* __restrict__ b2, float* __restrict__ abuf,
                       float* __restrict__ b2ws)
{
    __shared__ float d_s[12];
    __shared__ float red[36][12];
    const int tid = threadIdx.x;  // 512
    if (tid < 12) {
        const float N = 1533312.f;   // 8*18*22*22*22
        float mean = stats2[tid] / N;
        float var  = stats2[12 + tid] / N - mean * mean;
        float a = gamma[tid] * rsqrtf(var + EPS);
        abuf[tid] = a;
        d_s[tid] = beta[tid] - mean * a;
    }
    __syncthreads();
    if (tid < 432) {
        const int o = tid / 12, c = tid - o * 12;
        const float* p = W2 + o * 972 + c * 81;
        float ts = 0.f;
#pragma unroll
        for (int k = 0; k < 81; ++k) ts += p[k];
        red[o][c] = d_s[c] * ts;
    }
    __syncthreads();
    if (tid < 36) {
        float s = b2[tid];
#pragma unroll
        for (int c = 0; c < 12; ++c) s += red[tid][c];
        b2ws[tid] = s;
    }
}

// Build conv2 A-operand fragment-ordered weights Wf (BN-scaled).
__global__ void k_fin2(const float* __restrict__ W2, const float* __restrict__ abuf,
                       unsigned short* __restrict__ Wf)
{
    const int bi = blockIdx.x;       // 0..161
    const int lane = threadIdx.x;    // 0..63
    const int ch = bi & 1;
    const int tmp = bi >> 1;
    const int mt = tmp % 3;
    const int g = tmp / 3;
    const int kt = g / 9, g9 = g % 9, kd = g9 / 3, kh = g9 % 3;
    const int o = mt * 16 + (lane & 15);

    unsigned short vals[8];
#pragma unroll
    for (int j = 0; j < 8; ++j) {
        int k = ch * 32 + ((lane >> 4) << 3) + j;
        float v = 0.f;
        if (k < 48 && o < 36) {
            int kw = k >> 4, c = k & 15;
            if (c < 12)
                v = W2[o * 972 + c * 81 + kt * 27 + kd * 9 + kh * 3 + kw] * abuf[c];
        }
        vals[j] = f2bf(v);
    }
    uint4 pk;
    pk.x = (unsigned)vals[0] | ((unsigned)vals[1] << 16);
    pk.y = (unsigned)vals[2] | ((unsigned)vals[3] << 16);
    pk.z = (unsigned)vals[4] | ((unsigned)vals[5] << 16);
    pk.w = (unsigned)vals[6] | ((unsigned)vals[7] << 16);
    *(uint4*)(Wf + bi * 512 + lane * 8) = pk;
}

// MFMA implicit-GEMM conv2, v3:
//  - 512 threads (8 waves, balanced over 4 SIMDs), t-PAIR per block:
//    output planes (t0, t0+1) share staged slabs (plane0 tap kt, plane1 tap kt-1)
//    and share B-fragments -> 4 slabs / 2 planes, half the ds_read volume.
//  - slab double-buffer + A-fragment LDS double-buffer, both staged by
//    global_load_lds w=16, counted s_waitcnt vmcnt(2/8) + raw s_barrier
//    (never vmcnt(0) mid-loop). Main loop has NO other VMEM -> exact ledger.
//  - A-in-LDS kills the 8x per-wave Wf re-read from L2 (2.6MB -> 324KB/block).
//  - slab B-reads bank-swizzled: XOR byte-bit4 by ((within-row unit)>>3)&1,
//    applied on BOTH sides (pre-swizzled gload source + swizzled read base).
//  - grid 1280 = 8b x 8tp x 20d, XCD-bijective (b == XCD), d-contiguous per XCD.
__global__ __launch_bounds__(512, 2) void k_conv2m(
    const unsigned short* __restrict__ h1t, const unsigned short* __restrict__ Wf,
    const float* __restrict__ b2ws, float* __restrict__ out)
{
    __shared__ char lds[LDS_TOT];   // 122880 B -> 1 block/CU (by design)

    const int tid  = threadIdx.x;
    const int lane = tid & 63;
    const int wv   = tid >> 6;     // 0..7

    const int l   = blockIdx.x;
    const int b   = l & 7;         // == XCD under round-robin dispatch
    const int rem = l >> 3;        // 0..159
    const int d   = rem % 20;
    const int t0  = (rem / 20) * 2;

    const int n16 = lane & 15;
    const int q   = lane >> 4;

    // ---- staging helpers ----
    auto stage_slab = [&](int ktIn, int buf) {
        const unsigned short* base = h1t + (long)b * HTB + (long)(t0 + ktIn) * HTT
                                   + (long)d * HTD;
#pragma unroll
        for (int r = 0; r < 6; ++r) {
            int j = r * 512 + wv * 64 + lane;          // dest unit (0..3071)
            int f = ((j % 44) >> 3) & 1;               // swizzle bit
            gload16(base + (long)(j ^ f) * 8,
                    lds + buf * SLAB_B_SZ + (r * 512 + wv * 64) * 16);
        }
    };
    auto stage_A = [&](int tt) {   // stage A-frags for step tt into abuf[tt&1]
        const int dstb = ABUF_OFF + (tt & 1) * ABUF_SZ;
#pragma unroll
        for (int r = 0; r < 2; ++r) {
            int j  = wv * 96 + r * 32 + lane;          // dest unit (0..767)
            int fi = j >> 6;                           // frag 0..11
            int sl = j & 63;
            int pe = fi / 6;
            int r6 = fi - pe * 6;
            int mt = r6 >> 1, ch = r6 & 1;
            int gA = tt - pe * 9;
            gA = (gA >= 0 && gA < 27) ? gA : 0;        // clamp (garbage, unread)
            int idx = (gA * 3 + mt) * 2 + ch;
            gload16(Wf + idx * 512 + sl * 8,
                    lds + dstb + (wv * 96 + r * 32) * 16);
        }
    };

    // ---- per-tile setup: pos-tile ps -> pt = ps*8+wv (25 tiles over 8 waves) ----
    int rb0a[4], rb1a[4], pba[4];
    bool val[4];
#pragma unroll
    for (int ps = 0; ps < 4; ++ps) {
        int pt = ps * 8 + wv;
        val[ps] = pt < 25;
        int ptc = val[ps] ? pt : 0;
        int n = ptc * 16 + n16;                 // position 0..399
        int h = n / 20, w = n - h * 20;
        pba[ps] = n;
        int posb = n / 20 * 704 + w * 32;
        int u0 = 2 * w + q;                     // within-row unit of b0
        int u1 = 2 * w + 4 + (q & 1);           // within-row unit of b1
        rb0a[ps] = (posb + q * 16) ^ (((u0 >> 3) & 1) << 4);
        rb1a[ps] = (posb + (q & 1) * 16 + 64) ^ (((u1 >> 3) & 1) << 4);
        (void)h;
    }

    f32x4 acc[4][2][3];
#pragma unroll
    for (int ps = 0; ps < 4; ++ps)
#pragma unroll
        for (int pe = 0; pe < 2; ++pe)
#pragma unroll
            for (int mt = 0; mt < 3; ++mt)
                acc[ps][pe][mt] = (f32x4){0.f, 0.f, 0.f, 0.f};

    // ---- prologue: issue slab0 (6) + A(step0) (2); waits happen in step 0 ----
    stage_slab(0, 0);
    stage_A(0);

#define COMPUTE_STEP(KT, G9V, PE0, PE1)                                          \
  {                                                                              \
    const int g9_ = (G9V);                                                       \
    const int kd_ = g9_ / 3, kh_ = g9_ - kd_ * 3;                                \
    const int goff_ = kd_ * 15488 + kh_ * 704;                                   \
    const char* sbp_ = lds + ((KT) & 1) * SLAB_B_SZ;                             \
    const char* abp_ = lds + ABUF_OFF + (((KT) * 9 + g9_) & 1) * ABUF_SZ;        \
    bf16x8 Af0_[3][2], Af1_[3][2];                                               \
    if (PE0) {                                                                   \
      _Pragma("unroll") for (int mt = 0; mt < 3; ++mt)                           \
        _Pragma("unroll") for (int ch = 0; ch < 2; ++ch)                         \
          Af0_[mt][ch] = *(const bf16x8*)(abp_ + (mt * 2 + ch) * 1024 + lane * 16); \
    }                                                                            \
    if (PE1) {                                                                   \
      _Pragma("unroll") for (int mt = 0; mt < 3; ++mt)                           \
        _Pragma("unroll") for (int ch = 0; ch < 2; ++ch)                         \
          Af1_[mt][ch] = *(const bf16x8*)(abp_ + (6 + mt * 2 + ch) * 1024 + lane * 16); \
    }                                                                            \
    __builtin_amdgcn_s_setprio(1);                                               \
    _Pragma("unroll")                                                            \
    for (int ps = 0; ps < 4; ++ps) if (val[ps]) {                                \
      bf16x8 b0_ = *(const bf16x8*)(sbp_ + rb0a[ps] + goff_);                    \
      bf16x8 b1_ = *(const bf16x8*)(sbp_ + rb1a[ps] + goff_);                    \
      if (PE0) {                                                                 \
        _Pragma("unroll") for (int mt = 0; mt < 3; ++mt) {                       \
          acc[ps][0][mt] = __builtin_amdgcn_mfma_f32_16x16x32_bf16(Af0_[mt][0], b0_, acc[ps][0][mt], 0, 0, 0); \
          acc[ps][0][mt] = __builtin_amdgcn_mfma_f32_16x16x32_bf16(Af0_[mt][1], b1_, acc[ps][0][mt], 0, 0, 0); \
        }                                                                        \
      }                                                                          \
      if (PE1) {                                                                 \
        _Pragma("unroll") for (int mt = 0; mt < 3; ++mt) {                       \
          acc[ps][1][mt] = __builtin_amdgcn_mfma_f32_16x16x32_bf16(Af1_[mt][0], b0_, acc[ps][1][mt], 0, 0, 0); \
          acc[ps][1][mt] = __builtin_amdgcn_mfma_f32_16x16x32_bf16(Af1_[mt][1], b1_, acc[ps][1][mt], 0, 0, 0); \
        }                                                                        \
      }                                                                          \
    }                                                                            \
    __builtin_amdgcn_s_setprio(0);                                               \
  }

#define FULL_STEP(KT, G9V, VMN, DOSLAB)                                          \
  {                                                                              \
    const int s_ = (KT) * 9 + (G9V);                                             \
    if (s_ < 35) stage_A(s_ + 1);                                                \
    if (DOSLAB) stage_slab((KT) + 1, ((KT) + 1) & 1);                            \
    waitvm<VMN>();                                                               \
    __builtin_amdgcn_s_barrier();                                                \
    __builtin_amdgcn_sched_barrier(0);                                           \
    COMPUTE_STEP(KT, G9V, ((KT) < 3), ((KT) > 0))                                \
    __builtin_amdgcn_s_barrier();                                                \
  }

    // kt = 0 (plane0 only)
    for (int g9 = 0; g9 < 4; ++g9) FULL_STEP(0, g9, 2, false)
    FULL_STEP(0, 4, 8, true)
    FULL_STEP(0, 5, 8, false)
    for (int g9 = 6; g9 < 9; ++g9) FULL_STEP(0, g9, 2, false)
    // kt = 1 (both planes)
    for (int g9 = 0; g9 < 4; ++g9) FULL_STEP(1, g9, 2, false)
    FULL_STEP(1, 4, 8, true)
    FULL_STEP(1, 5, 8, false)
    for (int g9 = 6; g9 < 9; ++g9) FULL_STEP(1, g9, 2, false)
    // kt = 2 (both planes)
    for (int g9 = 0; g9 < 4; ++g9) FULL_STEP(2, g9, 2, false)
    FULL_STEP(2, 4, 8, true)
    FULL_STEP(2, 5, 8, false)
    for (int g9 = 6; g9 < 9; ++g9) FULL_STEP(2, g9, 2, false)
    // kt = 3 (plane1 only, no slab prefetch)
    for (int g9 = 0; g9 < 8; ++g9) FULL_STEP(3, g9, 2, false)
    FULL_STEP(3, 8, 0, false)

#undef FULL_STEP
#undef COMPUTE_STEP

    // ---- epilogue ----
    const long obase = (long)b * S2B + (long)d * S2D;
#pragma unroll
    for (int ps = 0; ps < 4; ++ps) if (val[ps]) {
#pragma unroll
        for (int pe = 0; pe < 2; ++pe) {
            const long ot = obase + (long)(t0 + pe) * S2T;
#pragma unroll
            for (int mt = 0; mt < 3; ++mt)
#pragma unroll
            for (int r = 0; r < 4; ++r) {
                const int o = mt * 16 + q * 4 + r;
                if (o < 36)
                    out[ot + (long)o * S2O + pba[ps]] =
                        fmaxf(acc[ps][pe][mt][r] + b2ws[o], 0.f);
            }
        }
    }
}

extern "C" void kernel_launch(void* const* d_in, const int* in_sizes, int n_in,
                              void* d_out, int out_size, void* d_ws, size_t ws_size,
                              hipStream_t stream) {
    const float* x     = (const float*)d_in[0];
    const float* W1    = (const float*)d_in[1];
    const float* b1    = (const float*)d_in[2];
    const float* gamma = (const float*)d_in[3];
    const float* beta  = (const float*)d_in[4];
    const float* W2    = (const float*)d_in[5];
    const float* b2    = (const float*)d_in[6];
    float* out = (float*)d_out;

    float* ws     = (float*)d_ws;
    float* stats2 = ws;                                  // 24 f
    float* abuf   = ws + 32;                             // 12 f
    float* b2ws   = ws + 64;                             // 36 f
    unsigned short* Wf1 = (unsigned short*)((char*)d_ws + 1024);    // 14336 B
    unsigned short* Wf  = (unsigned short*)((char*)d_ws + 16384);   // 165888 B
    float* part   = (float*)((char*)d_ws + 196608);      // 24*3168 f = 304128 B
    unsigned short* h1t = (unsigned short*)((char*)d_ws + 524288);  // 49.07 MB
    unsigned short* xt  = (unsigned short*)((char*)d_ws + 50331648); // 17.7 MB

    k_xt<<<dim3(24, 20, 8), 576, 0, stream>>>(x, xt);
    k_finW1<<<14, 64, 0, stream>>>(W1, Wf1);
    k_conv1m<<<3168, 512, 0, stream>>>(xt, Wf1, b1, h1t, part);
    k_red<<<24, 256, 0, stream>>>(part, stats2);
    k_fin1<<<1, 512, 0, stream>>>(stats2, gamma, beta, W2, b2, abuf, b2ws);
    k_fin2<<<162, 64, 0, stream>>>(W2, abuf, Wf);
    k_conv2m<<<1280, 512, 0, stream>>>(h1t, Wf, b2ws, out);
}

// Round 5
// 419.854 us; speedup vs baseline: 1.2179x; 1.0015x over previous
//
#include <hip/hip_runtime.h>

#define EPS 0.001f

typedef __attribute__((ext_vector_type(8))) short bf16x8;
typedef __attribute__((ext_vector_type(4))) short bf16x4;
typedef __attribute__((ext_vector_type(4))) float f32x4;

// ---- problem sizes ----
constexpr int Bn = 8, Tx = 20, Dx = 24, Hx = 24, Wx = 24;
constexpr int Cmid = 12, CoutN = 36;
constexpr int T1 = 18, D1 = 22;
constexpr int T2 = 16, D2 = 20;

// x strides (fp32)
constexpr int SXD = 576, SXT = 13824, SXC = 276480;
constexpr long SXB = 1105920;

// xt: [b][t20][d24][h24][w24][c4] bf16
constexpr int XTD = 2304, XTT = 55296;
constexpr long XTB = (long)Tx * XTT;     // 1105920

// h1t: [b][t18][d22][h22][w22][c16] bf16
constexpr int HTW = 16;
constexpr int HTH = 22 * 16;          // 352
constexpr int HTD = 22 * 22 * 16;     // 7744
constexpr int HTT = 22 * HTD;         // 170368
constexpr long HTB = (long)T1 * HTT;  // 3066624

// out strides (fp32)
constexpr int S2D = 400, S2T = 8000, S2O = 128000;
constexpr long S2B = 4608000;

constexpr int NBLK1 = 8 * 18 * 22;    // 3168 conv1m blocks

// conv2 LDS layout
constexpr int SLAB_B_SZ = 49152;            // 3072 units * 16B (2904 real + pad)
constexpr int ABUF_OFF  = 2 * SLAB_B_SZ;    // 98304
constexpr int ABUF_SZ   = 24576;            // 24 frags * 1024B (2 sub-steps x 12)
constexpr int LDS_TOT   = ABUF_OFF + 2 * ABUF_SZ;  // 147456

__device__ __forceinline__ unsigned short f2bf(float f) {
    unsigned u = __builtin_bit_cast(unsigned, f);
    u = (u + 0x7fffu + ((u >> 16) & 1u)) >> 16;
    return (unsigned short)u;
}

// async global->LDS, 16B per lane. LDS dest is wave-uniform base; HW adds lane*16.
__device__ __forceinline__ void gload16(const void* g, void* l) {
    __builtin_amdgcn_global_load_lds(
        (const __attribute__((address_space(1))) void*)g,
        (__attribute__((address_space(3))) void*)l, 16, 0, 0);
}

template<int N> __device__ __forceinline__ void waitvm() {
    asm volatile("s_waitcnt vmcnt(%0)" :: "i"(N) : "memory");
}

// x [b][cin][t][d][h][w] fp32 -> xt [b][t][d][h][w][c4] bf16
__global__ __launch_bounds__(576) void k_xt(const float* __restrict__ x,
                                            unsigned short* __restrict__ xt) {
    const int tid = threadIdx.x;          // 0..575 = h*24+w
    const int d = blockIdx.x, t = blockIdx.y, b = blockIdx.z;
    const float* src = x + (long)b * SXB + (long)t * SXT + (long)d * SXD + tid;
    float v0 = src[0];
    float v1 = src[SXC];
    float v2 = src[2 * SXC];
    float v3 = src[3 * SXC];
    uint2 p;
    p.x = (unsigned)f2bf(v0) | ((unsigned)f2bf(v1) << 16);
    p.y = (unsigned)f2bf(v2) | ((unsigned)f2bf(v3) << 16);
    *(uint2*)(xt + (long)b * XTB + (long)t * XTT + (long)d * XTD + tid * 4) = p;
}

// Build conv1 A-fragments Wf1[p=0..13][lane][8]
__global__ void k_finW1(const float* __restrict__ W1, unsigned short* __restrict__ Wf1) {
    const int p = blockIdx.x;        // 0..13
    const int lane = threadIdx.x;    // 0..63
    const int m = lane & 15;
    const int q = lane >> 4;
    unsigned short vals[8];
#pragma unroll
    for (int j = 0; j < 8; ++j) {
        int kk = q * 8 + j;
        int g = 2 * p + (kk >> 4);
        int r = kk & 15;
        int kw = r >> 2, cin = r & 3;
        float v = 0.f;
        if (m < 12 && kw < 3 && g < 27) {
            int kt = g / 9, g9 = g - kt * 9, kd = g9 / 3, kh = g9 - kd * 3;
            v = W1[m * 324 + cin * 81 + kt * 27 + kd * 9 + kh * 3 + kw];
        }
        vals[j] = f2bf(v);
    }
    uint4 pk;
    pk.x = (unsigned)vals[0] | ((unsigned)vals[1] << 16);
    pk.y = (unsigned)vals[2] | ((unsigned)vals[3] << 16);
    pk.z = (unsigned)vals[4] | ((unsigned)vals[5] << 16);
    pk.w = (unsigned)vals[6] | ((unsigned)vals[7] << 16);
    *(uint4*)(Wf1 + p * 512 + lane * 8) = pk;
}

// MFMA implicit-GEMM conv1. 1D grid 3168, XCD-swizzled. gload_lds staging.
__global__ __launch_bounds__(512, 4) void k_conv1m(
    const unsigned short* __restrict__ xt, const unsigned short* __restrict__ Wf1,
    const float* __restrict__ b1, unsigned short* __restrict__ h1t,
    float* __restrict__ part)
{
    __shared__ char lds[9 * 4608 + 16];
    __shared__ float ssum[8][12], ssq[8][12];

    const int tid  = threadIdx.x;
    const int lane = tid & 63;
    const int wv   = tid >> 6;     // 0..7

    // XCD-aware swizzle: 3168 % 8 == 0, each XCD gets one full b (396 blocks)
    const int l  = blockIdx.x;
    const int sw = (l & 7) * 396 + (l >> 3);
    const int d  = sw % 22;
    const int tt = sw / 22;
    const int t  = tt % 18;
    const int b  = tt / 18;
    const int bid = (b * 18 + t) * 22 + d;

    const int n16 = lane & 15;
    const int q   = lane >> 4;

    // stage 9 planes (p = kt*3+kd) via global_load_lds, 2592 units of 16B
    {
#pragma unroll
        for (int r = 0; r < 5; ++r) {
            int i = r * 512 + tid;
            int p = i / 288, rr = i - p * 288;
            int kt = p / 3, kd = p - kt * 3;
            const unsigned short* src = xt + (long)b * XTB + (long)(t + kt) * XTT
                                      + (long)(d + kd) * XTD + rr * 8;
            gload16(src, lds + (r * 512 + wv * 64) * 16);
        }
        if (tid < 32) {   // tail 32 units, wave0 lanes 0..31 (exec-masked)
            int i = 2560 + tid;
            int p = i / 288, rr = i - p * 288;   // all p == 8
            int kt = p / 3, kd = p - kt * 3;
            const unsigned short* src = xt + (long)b * XTB + (long)(t + kt) * XTT
                                      + (long)(d + kd) * XTD + rr * 8;
            gload16(src, lds + 2560 * 16);
        }
    }

    // A fragments (global, L2-resident)
    bf16x8 A[14];
#pragma unroll
    for (int p = 0; p < 14; ++p)
        A[p] = *(const bf16x8*)(Wf1 + p * 512 + lane * 8);

    // per-tile position info
    int hh[4], ww[4], nn[4];
#pragma unroll
    for (int u = 0; u < 4; ++u) {
        int n = (wv * 4 + u) * 16 + n16;
        nn[u] = n;
        int nc = n < 484 ? n : 483;
        hh[u] = nc / 22;
        ww[u] = nc - hh[u] * 22;
    }

    f32x4 acc[4];
#pragma unroll
    for (int u = 0; u < 4; ++u) acc[u] = (f32x4){0.f, 0.f, 0.f, 0.f};

    __syncthreads();   // drains vmcnt -> staged planes visible

#pragma unroll
    for (int p = 0; p < 14; ++p) {
        int gq = 2 * p + (q >> 1);
        int gc = gq < 27 ? gq : 26;
        int kt = gc / 9, g9 = gc - kt * 9, kd = g9 / 3, kh = g9 - kd * 3;
        const int off = (kt * 3 + kd) * 4608 + kh * 192 + (q & 1) * 16;
#pragma unroll
        for (int u = 0; u < 4; ++u) {
            const int addr = off + hh[u] * 192 + ww[u] * 8;
            bf16x4 lo = *(const bf16x4*)(lds + addr);
            bf16x4 hi = *(const bf16x4*)(lds + addr + 8);
            bf16x8 bb;
            bb[0] = lo[0]; bb[1] = lo[1]; bb[2] = lo[2]; bb[3] = lo[3];
            bb[4] = hi[0]; bb[5] = hi[1]; bb[6] = hi[2]; bb[7] = hi[3];
            acc[u] = __builtin_amdgcn_mfma_f32_16x16x32_bf16(A[p], bb, acc[u], 0, 0, 0);
        }
    }

    // epilogue: D row = q*4+r = cout, col = n16 = position
    const int c0 = q * 4;
    float bias[4];
#pragma unroll
    for (int r = 0; r < 4; ++r) bias[r] = (c0 + r) < 12 ? b1[c0 + r] : 0.f;

    float ls[4] = {0.f, 0.f, 0.f, 0.f}, lq[4] = {0.f, 0.f, 0.f, 0.f};
#pragma unroll
    for (int u = 0; u < 4; ++u) {
        const bool valid = nn[u] < 484;
        float v[4];
#pragma unroll
        for (int r = 0; r < 4; ++r) {
            float val = fmaxf(acc[u][r] + bias[r], 0.f);
            v[r] = val;
            if (valid) { ls[r] += val; lq[r] += val * val; }
        }
        if (valid) {
            const long ob = (long)b * HTB + (long)t * HTT + (long)d * HTD
                          + (long)hh[u] * HTH + (long)ww[u] * HTW + c0;
            uint2 pk;
            pk.x = (unsigned)f2bf(v[0]) | ((unsigned)f2bf(v[1]) << 16);
            pk.y = (unsigned)f2bf(v[2]) | ((unsigned)f2bf(v[3]) << 16);
            *(uint2*)(h1t + ob) = pk;
        }
    }

    // stats: reduce over n16 within q-group
#pragma unroll
    for (int off = 8; off > 0; off >>= 1) {
#pragma unroll
        for (int r = 0; r < 4; ++r) {
            ls[r] += __shfl_xor(ls[r], off);
            lq[r] += __shfl_xor(lq[r], off);
        }
    }
    if (n16 == 0 && q < 3) {
#pragma unroll
        for (int r = 0; r < 4; ++r) {
            ssum[wv][c0 + r] = ls[r];
            ssq[wv][c0 + r] = lq[r];
        }
    }
    __syncthreads();
    // part transposed: part[ch][bid] so k_red reads coalesced
    if (tid < 12) {
        float s = 0.f;
#pragma unroll
        for (int i = 0; i < 8; ++i) s += ssum[i][tid];
        part[tid * NBLK1 + bid] = s;
    } else if (tid < 24) {
        float s = 0.f;
#pragma unroll
        for (int i = 0; i < 8; ++i) s += ssq[i][tid - 12];
        part[tid * NBLK1 + bid] = s;
    }
}

// deterministic cross-block reduction: 24 blocks, one per stat channel
__global__ void k_red(const float* __restrict__ part, float* __restrict__ stats2) {
    __shared__ float s[256];
    const int c = blockIdx.x;
    const int tid = threadIdx.x;
    float acc = 0.f;
    for (int i = tid; i < NBLK1; i += 256) acc += part[c * NBLK1 + i];
    s[tid] = acc;
    __syncthreads();
    for (int off = 128; off > 0; off >>= 1) {
        if (tid < off) s[tid] += s[tid + off];
        __syncthreads();
    }
    if (tid == 0) stats2[c] = s[0];
}

// finalize BN, parallel tap-sum: 432 threads each do one (o,c) 81-tap sum
__global__ void k_fin1(const float* __restrict__ stats2, const float* __restrict__ gamma,
                       const float* __restrict__ beta, const float* __restrict__ W2,
                       const float* __restrict__ b2, float* __restrict__ abuf,
                       float* __restrict__ b2ws)
{
    __shared__ float d_s[12];
    __shared__ float red[36][12];
    const int tid = threadIdx.x;  // 512
    if (tid < 12) {
        const float N = 1533312.f;   // 8*18*22*22*22
        float mean = stats2[tid] / N;
        float var  = stats2[12 + tid] / N - mean * mean;
        float a = gamma[tid] * rsqrtf(var + EPS);
        abuf[tid] = a;
        d_s[tid] = beta[tid] - mean * a;
    }
    __syncthreads();
    if (tid < 432) {
        const int o = tid / 12, c = tid - o * 12;
        const float* p = W2 + o * 972 + c * 81;
        float ts = 0.f;
#pragma unroll
        for (int k = 0; k < 81; ++k) ts += p[k];
        red[o][c] = d_s[c] * ts;
    }
    __syncthreads();
    if (tid < 36) {
        float s = b2[tid];
#pragma unroll
        for (int c = 0; c < 12; ++c) s += red[tid][c];
        b2ws[tid] = s;
    }
}

// Build conv2 A-operand fragment-ordered weights Wf (BN-scaled).
__global__ void k_fin2(const float* __restrict__ W2, const float* __restrict__ abuf,
                       unsigned short* __restrict__ Wf)
{
    const int bi = blockIdx.x;       // 0..161
    const int lane = threadIdx.x;    // 0..63
    const int ch = bi & 1;
    const int tmp = bi >> 1;
    const int mt = tmp % 3;
    const int g = tmp / 3;
    const int kt = g / 9, g9 = g % 9, kd = g9 / 3, kh = g9 % 3;
    const int o = mt * 16 + (lane & 15);

    unsigned short vals[8];
#pragma unroll
    for (int j = 0; j < 8; ++j) {
        int k = ch * 32 + ((lane >> 4) << 3) + j;
        float v = 0.f;
        if (k < 48 && o < 36) {
            int kw = k >> 4, c = k & 15;
            if (c < 12)
                v = W2[o * 972 + c * 81 + kt * 27 + kd * 9 + kh * 3 + kw] * abuf[c];
        }
        vals[j] = f2bf(v);
    }
    uint4 pk;
    pk.x = (unsigned)vals[0] | ((unsigned)vals[1] << 16);
    pk.y = (unsigned)vals[2] | ((unsigned)vals[3] << 16);
    pk.z = (unsigned)vals[4] | ((unsigned)vals[5] << 16);
    pk.w = (unsigned)vals[6] | ((unsigned)vals[7] << 16);
    *(uint4*)(Wf + bi * 512 + lane * 8) = pk;
}

// MFMA implicit-GEMM conv2, v5 = v3 skeleton at 2x coarser barrier grain:
//  - 18 super-steps; each = {stage_A(next, 24 frags); [slab @ s5/s9];
//    counted waitvm; s_barrier; compute sub-steps 2s, 2s+1; s_barrier}.
//    Identical sync skeleton to the verified v3 kernel, half the barriers.
//  - sub-step tt = KT*9+g9 (KT=tt/9): plane0 tap g=tt (tt<27), plane1 tap
//    g=tt-9 (tt>=9). Slab buffer = KT&1 (s0..s3 ping-pong; s2 staged @ s==5,
//    s3 @ s==9 -- both-sides protected by the trailing barrier of s-1).
//  - A-staging: 24 frags x 1KB, exactly 3 gload16/wave (frag = 3*wv+r).
//  - counted vmcnt (FIFO-verified, A issued before slab):
//    N=9 at s in {5,6,9,10}; N=0 at s=17; else N=3.
//  - LDS 147456: 2x48K slab dbuf + 2x24K A dbuf -> 1 block/CU, 8 waves.
__global__ __launch_bounds__(512, 2) void k_conv2m(
    const unsigned short* __restrict__ h1t, const unsigned short* __restrict__ Wf,
    const float* __restrict__ b2ws, float* __restrict__ out)
{
    __shared__ char lds[LDS_TOT];

    const int tid  = threadIdx.x;
    const int lane = tid & 63;
    const int wv   = tid >> 6;     // 0..7

    const int l   = blockIdx.x;
    const int b   = l & 7;         // == XCD under round-robin dispatch
    const int rem = l >> 3;        // 0..159
    const int d   = rem % 20;
    const int t0  = (rem / 20) * 2;

    const int n16 = lane & 15;
    const int q   = lane >> 4;

    // ---- staging helpers ----
    auto stage_slab = [&](int t_in, int buf) {
        const unsigned short* base = h1t + (long)b * HTB + (long)t_in * HTT
                                   + (long)d * HTD;
#pragma unroll
        for (int r = 0; r < 6; ++r) {
            int j = r * 512 + wv * 64 + lane;          // dest unit (0..3071)
            int f = ((j % 44) >> 3) & 1;               // swizzle bit
            gload16(base + (long)(j ^ f) * 8,
                    lds + buf * SLAB_B_SZ + (r * 512 + wv * 64) * 16);
        }
    };
    // stage 24 A-frags for super-step ss (sub-steps 2ss, 2ss+1): 3 gloads/wave
    auto stage_A2 = [&](int ss) {
        const int dstb = ABUF_OFF + (ss & 1) * ABUF_SZ;
#pragma unroll
        for (int r = 0; r < 3; ++r) {
            int frag = wv * 3 + r;                 // 0..23, wave-uniform
            int e   = frag / 12, r12 = frag - e * 12;
            int pe  = r12 / 6,   r6  = r12 - pe * 6;
            int mt  = r6 >> 1,   ch  = r6 & 1;
            int ttv = 2 * ss + e;
            int gA  = ttv - pe * 9;
            gA = (gA >= 0 && gA < 27) ? gA : 0;    // clamp (garbage, unread)
            int idx = (gA * 3 + mt) * 2 + ch;
            gload16(Wf + idx * 512 + lane * 8, lds + dstb + frag * 1024);
        }
    };

    // ---- per-tile setup: pos-tile ps -> pt = ps*8+wv (25 tiles over 8 waves) ----
    int rb0a[4], rb1a[4], pba[4];
    bool val[4];
#pragma unroll
    for (int ps = 0; ps < 4; ++ps) {
        int pt = ps * 8 + wv;
        val[ps] = pt < 25;
        int ptc = val[ps] ? pt : 0;
        int n = ptc * 16 + n16;                 // position 0..399
        int h = n / 20, w = n - h * 20;
        pba[ps] = n;
        int posb = h * 704 + w * 32;
        int u0 = 2 * w + q;                     // within-row unit of b0
        int u1 = 2 * w + 4 + (q & 1);           // within-row unit of b1
        rb0a[ps] = (posb + q * 16) ^ (((u0 >> 3) & 1) << 4);
        rb1a[ps] = (posb + (q & 1) * 16 + 64) ^ (((u1 >> 3) & 1) << 4);
    }

    f32x4 acc[4][2][3];
#pragma unroll
    for (int ps = 0; ps < 4; ++ps)
#pragma unroll
        for (int pe = 0; pe < 2; ++pe)
#pragma unroll
            for (int mt = 0; mt < 3; ++mt)
                acc[ps][pe][mt] = (f32x4){0.f, 0.f, 0.f, 0.f};

    // one sub-step: 6-12 A ds_reads + 8 B ds_reads + up to 48 MFMA
    auto compute_tt = [&](int ttv, const char* abp_e) {
        const int KT = ttv / 9;
        const int g9 = ttv - KT * 9;
        const int kd = g9 / 3, kh = g9 - kd * 3;
        const int goff = kd * 15488 + kh * 704;
        const char* sbp = lds + (KT & 1) * SLAB_B_SZ;
        const bool PE0 = (ttv < 27), PE1 = (ttv >= 9);
        bf16x8 Af0[3][2], Af1[3][2];
        if (PE0) {
#pragma unroll
            for (int mt = 0; mt < 3; ++mt)
#pragma unroll
                for (int ch = 0; ch < 2; ++ch)
                    Af0[mt][ch] = *(const bf16x8*)(abp_e + (mt * 2 + ch) * 1024 + lane * 16);
        }
        if (PE1) {
#pragma unroll
            for (int mt = 0; mt < 3; ++mt)
#pragma unroll
                for (int ch = 0; ch < 2; ++ch)
                    Af1[mt][ch] = *(const bf16x8*)(abp_e + (6 + mt * 2 + ch) * 1024 + lane * 16);
        }
        __builtin_amdgcn_s_setprio(1);
#pragma unroll
        for (int ps = 0; ps < 4; ++ps) if (val[ps]) {
            bf16x8 b0 = *(const bf16x8*)(sbp + rb0a[ps] + goff);
            bf16x8 b1 = *(const bf16x8*)(sbp + rb1a[ps] + goff);
            if (PE0) {
#pragma unroll
                for (int mt = 0; mt < 3; ++mt) {
                    acc[ps][0][mt] = __builtin_amdgcn_mfma_f32_16x16x32_bf16(Af0[mt][0], b0, acc[ps][0][mt], 0, 0, 0);
                    acc[ps][0][mt] = __builtin_amdgcn_mfma_f32_16x16x32_bf16(Af0[mt][1], b1, acc[ps][0][mt], 0, 0, 0);
                }
            }
            if (PE1) {
#pragma unroll
                for (int mt = 0; mt < 3; ++mt) {
                    acc[ps][1][mt] = __builtin_amdgcn_mfma_f32_16x16x32_bf16(Af1[mt][0], b0, acc[ps][1][mt], 0, 0, 0);
                    acc[ps][1][mt] = __builtin_amdgcn_mfma_f32_16x16x32_bf16(Af1[mt][1], b1, acc[ps][1][mt], 0, 0, 0);
                }
            }
        }
        __builtin_amdgcn_s_setprio(0);
    };

    // ---- prologue: slabs s0,s1 + A(super-step 0) ----
    stage_slab(t0 + 0, 0);
    stage_slab(t0 + 1, 1);
    stage_A2(0);

    // ---- 18 super-steps ----
    for (int s = 0; s < 18; ++s) {
        if (s < 17) stage_A2(s + 1);               // A first (FIFO ledger)
        if (s == 5) stage_slab(t0 + 2, 0);         // buf0 free after s4 (trail barrier)
        if (s == 9) stage_slab(t0 + 3, 1);         // buf1 free after s8

        if (s == 17)                               waitvm<0>();
        else if (s == 5 || s == 6 || s == 9 || s == 10) waitvm<9>();
        else                                       waitvm<3>();
        __builtin_amdgcn_s_barrier();
        __builtin_amdgcn_sched_barrier(0);

        const char* abp = lds + ABUF_OFF + (s & 1) * ABUF_SZ;
        compute_tt(2 * s,     abp);
        compute_tt(2 * s + 1, abp + 12288);

        __builtin_amdgcn_s_barrier();
    }

    // ---- epilogue ----
    const long obase = (long)b * S2B + (long)d * S2D;
#pragma unroll
    for (int ps = 0; ps < 4; ++ps) if (val[ps]) {
#pragma unroll
        for (int pe = 0; pe < 2; ++pe) {
            const long ot = obase + (long)(t0 + pe) * S2T;
#pragma unroll
            for (int mt = 0; mt < 3; ++mt)
#pragma unroll
            for (int r = 0; r < 4; ++r) {
                const int o = mt * 16 + q * 4 + r;
                if (o < 36)
                    out[ot + (long)o * S2O + pba[ps]] =
                        fmaxf(acc[ps][pe][mt][r] + b2ws[o], 0.f);
            }
        }
    }
}

extern "C" void kernel_launch(void* const* d_in, const int* in_sizes, int n_in,
                              void* d_out, int out_size, void* d_ws, size_t ws_size,
                              hipStream_t stream) {
    const float* x     = (const float*)d_in[0];
    const float* W1    = (const float*)d_in[1];
    const float* b1    = (const float*)d_in[2];
    const float* gamma = (const float*)d_in[3];
    const float* beta  = (const float*)d_in[4];
    const float* W2    = (const float*)d_in[5];
    const float* b2    = (const float*)d_in[6];
    float* out = (float*)d_out;

    float* ws     = (float*)d_ws;
    float* stats2 = ws;                                  // 24 f
    float* abuf   = ws + 32;                             // 12 f
    float* b2ws   = ws + 64;                             // 36 f
    unsigned short* Wf1 = (unsigned short*)((char*)d_ws + 1024);    // 14336 B
    unsigned short* Wf  = (unsigned short*)((char*)d_ws + 16384);   // 165888 B
    float* part   = (float*)((char*)d_ws + 196608);      // 24*3168 f = 304128 B
    unsigned short* h1t = (unsigned short*)((char*)d_ws + 524288);  // 49.07 MB
    unsigned short* xt  = (unsigned short*)((char*)d_ws + 50331648); // 17.7 MB

    k_xt<<<dim3(24, 20, 8), 576, 0, stream>>>(x, xt);
    k_finW1<<<14, 64, 0, stream>>>(W1, Wf1);
    k_conv1m<<<3168, 512, 0, stream>>>(xt, Wf1, b1, h1t, part);
    k_red<<<24, 256, 0, stream>>>(part, stats2);
    k_fin1<<<1, 512, 0, stream>>>(stats2, gamma, beta, W2, b2, abuf, b2ws);
    k_fin2<<<162, 64, 0, stream>>>(W2, abuf, Wf);
    k_conv2m<<<1280, 512, 0, stream>>>(h1t, Wf, b2ws, out);
}